// Round 12
// baseline (1448.079 us; speedup 1.0000x reference)
//
#include <hip/hip_runtime.h>
#include <hip/hip_fp16.h>
#include <math.h>

// Problem constants (match reference)
#define N_PTS   192000
#define NPATCH  4000      // N/48
#define PK      48        // patch size
#define NH      4         // heads
#define HD      16        // head dim

// Inline erf (Abramowitz & Stegun 7.1.26, |eps| <= 1.5e-7), no libm call.
__device__ __forceinline__ float erf_inl(float x) {
    float ax = fabsf(x);
    float t = 1.0f / fmaf(0.3275911f, ax, 1.0f);
    float poly = fmaf(1.061405429f, t, -1.453152027f);
    poly = fmaf(poly, t, 1.421413741f);
    poly = fmaf(poly, t, -0.284496736f);
    poly = fmaf(poly, t, 0.254829592f);
    poly *= t;
    float e = __expf(-ax * ax);          // native v_exp_f32
    float r = 1.0f - poly * e;
    return copysignf(r, x);
}

__device__ __forceinline__ float gelu_exact(float x) {
    return 0.5f * x * (1.0f + erf_inl(x * 0.70710678118654752f));
}

// ---------------------------------------------------------------------------
// K1: per-point (lane=point): softmax(seg,20)+coord -> feat -> LN1 -> qkv
// EXACT R8/R10/R11-validated version — byte-identical.
// ---------------------------------------------------------------------------
__global__ __launch_bounds__(256) void k_in_qkv(
    const float* __restrict__ seg, const float* __restrict__ coord,
    const float* __restrict__ W_in, const float* __restrict__ b_in,
    const float* __restrict__ g1, const float* __restrict__ be1,
    const float* __restrict__ W_qkv, const float* __restrict__ b_qkv,
    float* __restrict__ feat_out, float* __restrict__ qkv_out)
{
    int i = blockIdx.x * 256 + threadIdx.x;
    if (i >= N_PTS) return;

    float iv[23];
    {
        const float* s = seg + (size_t)i * 20;
        float mx = -1e30f;
        #pragma unroll
        for (int j = 0; j < 20; ++j) { iv[j] = s[j]; mx = fmaxf(mx, iv[j]); }
        float sum = 0.f;
        #pragma unroll
        for (int j = 0; j < 20; ++j) { iv[j] = __expf(iv[j] - mx); sum += iv[j]; }
        float r = 1.f / sum;
        #pragma unroll
        for (int j = 0; j < 20; ++j) iv[j] *= r;
        iv[20] = coord[(size_t)i*3 + 0];
        iv[21] = coord[(size_t)i*3 + 1];
        iv[22] = coord[(size_t)i*3 + 2];
    }

    // feat = iv @ W_in + b_in   (23x64), W_in row-major [23][64]
    float f[64];
    #pragma unroll
    for (int c = 0; c < 64; ++c) {
        float a = b_in[c];
        #pragma unroll
        for (int j = 0; j < 23; ++j) a = fmaf(iv[j], W_in[j*64 + c], a);
        f[c] = a;
    }
    // store feat (residual use in K3)
    {
        float4* fd = (float4*)(feat_out + (size_t)i * 64);
        #pragma unroll
        for (int c4 = 0; c4 < 16; ++c4)
            fd[c4] = make_float4(f[4*c4], f[4*c4+1], f[4*c4+2], f[4*c4+3]);
    }
    // LN1
    {
        float m = 0.f;
        #pragma unroll
        for (int c = 0; c < 64; ++c) m += f[c];
        m *= (1.f/64.f);
        float v = 0.f;
        #pragma unroll
        for (int c = 0; c < 64; ++c) { float d = f[c]-m; v = fmaf(d, d, v); }
        v *= (1.f/64.f);
        float rs = 1.f / sqrtf(v + 1e-5f);
        #pragma unroll
        for (int c = 0; c < 64; ++c) f[c] = (f[c]-m)*rs*g1[c] + be1[c];
    }
    // qkv = h @ W_qkv + b_qkv   (64x192), W_qkv row-major [64][192]
    {
        float* qd = qkv_out + (size_t)i * 192;
        for (int t4 = 0; t4 < 48; ++t4) {
            const float* bq = b_qkv + t4*4;
            float ax = bq[0], ay = bq[1], az = bq[2], aw = bq[3];
            const float* w = W_qkv + t4*4;
            #pragma unroll
            for (int c = 0; c < 64; ++c) {
                float h = f[c];
                const float* wr = w + c*192;
                ax = fmaf(h, wr[0], ax); ay = fmaf(h, wr[1], ay);
                az = fmaf(h, wr[2], az); aw = fmaf(h, wr[3], aw);
            }
            ((float4*)qd)[t4] = make_float4(ax, ay, az, aw);
        }
    }
}

// ---------------------------------------------------------------------------
// K2: windowed attention — R11-validated (online softmax, transposed rpe).
// Byte-identical.
// ---------------------------------------------------------------------------
__global__ __launch_bounds__(256) void k_attn(
    const float* __restrict__ qkv, const int* __restrict__ order,
    const int* __restrict__ grid_coord, const float* __restrict__ rpe,
    float* __restrict__ outb)
{
    __shared__ float q_s[NH][PK][17];
    __shared__ float k_s[NH][PK][HD];
    __shared__ float v_s[NH][PK][HD];
    __shared__ float rpe_s[276];        // [h][69] transposed layout
    __shared__ int   ord_s[PK];
    __shared__ int   gc_s[PK][3];

    int p = blockIdx.x;
    int tid = threadIdx.x;

    if (tid < PK) ord_s[tid] = order[p*PK + tid];
    for (int t = tid; t < 276; t += 256) {
        int hh2 = t / 69;               // dest head
        int idx = t - hh2 * 69;         // dest rpe index
        rpe_s[t] = rpe[idx*4 + hh2];    // src layout [69][4]
    }
    __syncthreads();

    if (tid < PK) {
        int row = ord_s[tid];
        gc_s[tid][0] = grid_coord[(size_t)row*3 + 0];
        gc_s[tid][1] = grid_coord[(size_t)row*3 + 1];
        gc_s[tid][2] = grid_coord[(size_t)row*3 + 2];
    }
    {
        int lane = tid & 63;
        int hh = lane >> 4, dd = lane & 15;
        for (int rr = tid >> 6; rr < PK; rr += 4) {
            const float* src = qkv + (size_t)ord_s[rr] * 192;
            float qv = src[lane];
            float kv = src[64 + lane];
            float vv = src[128 + lane];
            q_s[hh][rr][dd] = qv;
            k_s[hh][rr][dd] = kv;
            v_s[hh][rr][dd] = vv;
        }
    }
    __syncthreads();

    int h = tid >> 6;
    int r = tid & 63;
    if (r >= PK) return;

    float qr[HD];
    #pragma unroll
    for (int d = 0; d < HD; ++d) qr[d] = q_s[h][r][d];
    int gx = gc_s[r][0], gy = gc_s[r][1], gz = gc_s[r][2];
    int h69 = h * 69;

    // online softmax + PV: no score array, no scratch
    float m_run = -1e30f, l_run = 0.f;
    float acc[HD];
    #pragma unroll
    for (int d = 0; d < HD; ++d) acc[d] = 0.f;

    #pragma unroll 4
    for (int m = 0; m < PK; ++m) {
        float a = 0.f;
        #pragma unroll
        for (int d = 0; d < HD; ++d) a = fmaf(qr[d], k_s[h][m][d], a);
        a *= 0.25f;
        int i0 = min(max(gx - gc_s[m][0], -11), 11) + 11;
        int i1 = min(max(gy - gc_s[m][1], -11), 11) + 34;
        int i2 = min(max(gz - gc_s[m][2], -11), 11) + 57;
        a += rpe_s[h69 + i0] + rpe_s[h69 + i1] + rpe_s[h69 + i2];

        float m_new = fmaxf(m_run, a);
        float scale = __expf(m_run - m_new);   // 0 on first iter (exp(-inf))
        float pvv   = __expf(a - m_new);
        l_run = fmaf(l_run, scale, pvv);
        #pragma unroll
        for (int d = 0; d < HD; ++d)
            acc[d] = fmaf(acc[d], scale, pvv * v_s[h][m][d]);
        m_run = m_new;
    }
    float rinv = 1.f / l_run;

    {
        float* dst = outb + (size_t)ord_s[r]*64 + h*HD;
        float4* d4 = (float4*)dst;
        #pragma unroll
        for (int d4i = 0; d4i < 4; ++d4i)
            d4[d4i] = make_float4(acc[4*d4i]*rinv, acc[4*d4i+1]*rinv,
                                  acc[4*d4i+2]*rinv, acc[4*d4i+3]*rinv);
    }
}

// ---------------------------------------------------------------------------
// K3: THIS ROUND — 2 threads per point, split BY WAVE (waves 0-1 = half0,
// waves 2-3 = half1 of the block's 128 points). Doubles wave count
// (3000 -> 6000, occupancy 2.9 -> ~4/SIMD) while keeping ALL weight
// addresses wave-uniform (scalar-load path preserved). Cross-half data via
// barrier-separated LDS phases: fp16 shh rows (R8-validated mechanism,
// +2-half pad -> conflict-free), f32 pex for FFN/head partials.
// Per-thread FMA halves to ~19.6k; live set ~120 floats -> no spill.
// half h owns channels [32h,32h+32) and hidden [128h,128h+128).
// ---------------------------------------------------------------------------
__global__ __launch_bounds__(256) void k_ffn(
    const float* __restrict__ outb, const float* __restrict__ featb,
    const float* __restrict__ W_attn, const float* __restrict__ b_attn,
    const float* __restrict__ g2, const float* __restrict__ be2,
    const float* __restrict__ W_f1, const float* __restrict__ b_f1,
    const float* __restrict__ W_f2, const float* __restrict__ b_f2,
    const float* __restrict__ W_h1, const float* __restrict__ b_h1,
    const float* __restrict__ W_h2, const float* __restrict__ b_h2,
    float* __restrict__ out)
{
    __shared__ __half shh[128][66];     // 16.9 KB; hh[pt][c], row pad 33 words
    __shared__ float  pex[2][16][128];  // 16 KB; partial-sum exchange
    __shared__ float  sred[2][128][2];  // 2 KB;  LN2 (sum, sumsq)

    int tid  = threadIdx.x;
    int ptb  = tid & 127;               // point-in-block
    int half = tid >> 7;                // waves 0-1 -> 0, waves 2-3 -> 1
    int cb   = half * 32;               // owned channel base (wave-uniform)
    size_t i = (size_t)blockIdx.x * 128 + ptb;   // grid exact: 1500*128 = N

    // ---- attn-out proj into own 32 channels (o streamed in 16-chunks) ----
    float f[32];
    #pragma unroll
    for (int c = 0; c < 32; ++c) f[c] = b_attn[cb + c];
    for (int kc = 0; kc < 4; ++kc) {
        float o16[16];
        const float4* os = (const float4*)(outb + i * 64 + kc * 16);
        #pragma unroll
        for (int q = 0; q < 4; ++q) {
            float4 t = os[q];
            o16[4*q]=t.x; o16[4*q+1]=t.y; o16[4*q+2]=t.z; o16[4*q+3]=t.w;
        }
        #pragma unroll
        for (int j = 0; j < 16; ++j) {
            float vv = o16[j];
            const float* w = W_attn + (kc*16 + j)*64 + cb;   // wave-uniform
            #pragma unroll
            for (int c = 0; c < 32; ++c) f[c] = fmaf(vv, w[c], f[c]);
        }
    }
    // + residual feat (own 32 channels)
    {
        const float4* fs = (const float4*)(featb + i * 64 + cb);
        #pragma unroll
        for (int c4 = 0; c4 < 8; ++c4) {
            float4 t = fs[c4];
            f[4*c4]+=t.x; f[4*c4+1]+=t.y; f[4*c4+2]+=t.z; f[4*c4+3]+=t.w;
        }
    }
    // ---- LN2: cross-half (sum, sumsq) via LDS ----
    {
        float s0 = 0.f, q0 = 0.f;
        #pragma unroll
        for (int c = 0; c < 32; ++c) { s0 += f[c]; q0 = fmaf(f[c], f[c], q0); }
        sred[half][ptb][0] = s0;
        sred[half][ptb][1] = q0;
    }
    __syncthreads();
    {
        float S = sred[half^1][ptb][0] + sred[half][ptb][0];
        float Q = sred[half^1][ptb][1] + sred[half][ptb][1];
        float m = S * (1.f/64.f);
        float var = Q * (1.f/64.f) - m * m;
        float rs = 1.f / sqrtf(var + 1e-5f);
        #pragma unroll
        for (int c = 0; c < 32; ++c)
            shh[ptb][cb + c] = __float2half((f[c]-m)*rs*g2[cb+c] + be2[cb+c]);
    }
    __syncthreads();

    // ---- FFN: own 128 hidden units, partial sums over ALL 64 channels ----
    float p[64];
    #pragma unroll
    for (int c = 0; c < 64; ++c) p[c] = 0.f;
    for (int ch = 0; ch < 8; ++ch) {
        int hb = half * 128 + ch * 16;                  // wave-uniform
        float a[16];
        #pragma unroll
        for (int t = 0; t < 16; ++t) a[t] = b_f1[hb + t];
        const __half2* hrow = (const __half2*)&shh[ptb][0];
        #pragma unroll
        for (int c2 = 0; c2 < 32; ++c2) {
            __half2 hp = hrow[c2];
            float h0 = __half2float(hp.x);
            float h1 = __half2float(hp.y);
            const float* w0 = W_f1 + (size_t)(2*c2) * 256 + hb;
            #pragma unroll
            for (int t = 0; t < 16; ++t) a[t] = fmaf(h0, w0[t], a[t]);
            #pragma unroll
            for (int t = 0; t < 16; ++t) a[t] = fmaf(h1, w0[256 + t], a[t]);
        }
        #pragma unroll
        for (int t = 0; t < 16; ++t) a[t] = gelu_exact(a[t]);
        #pragma unroll
        for (int t = 0; t < 16; ++t) {
            float av = a[t];
            const float* w2 = W_f2 + (size_t)(hb + t) * 64;  // wave-uniform
            #pragma unroll
            for (int c = 0; c < 64; ++c) p[c] = fmaf(av, w2[c], p[c]);
        }
    }
    // ---- p exchange: 2 staggered rounds of 16 channels ----
    int pcb = 32 - cb;   // partner's channel base
    __syncthreads();     // shh reads done; pex about to be (re)used
    #pragma unroll
    for (int j = 0; j < 16; ++j) pex[half][j][ptb] = p[pcb + j];
    __syncthreads();
    #pragma unroll
    for (int j = 0; j < 16; ++j)
        f[j] += b_f2[cb + j] + p[cb + j] + pex[half^1][j][ptb];
    __syncthreads();     // WAR before round 1
    #pragma unroll
    for (int j = 0; j < 16; ++j) pex[half][j][ptb] = p[pcb + 16 + j];
    __syncthreads();
    #pragma unroll
    for (int j = 0; j < 16; ++j)
        f[16+j] += b_f2[cb + 16 + j] + p[cb + 16 + j] + pex[half^1][j][ptb];

    // ---- head: partials over own channels, half1 -> half0, half0 finishes --
    float gp[32];
    #pragma unroll
    for (int t = 0; t < 32; ++t) gp[t] = 0.f;
    #pragma unroll
    for (int c = 0; c < 32; ++c) {
        float vv = f[c];
        const float* w = W_h1 + (size_t)(cb + c) * 32;   // wave-uniform
        #pragma unroll
        for (int t = 0; t < 32; ++t) gp[t] = fmaf(vv, w[t], gp[t]);
    }
    __syncthreads();     // WAR on pex
    if (half == 1) {
        #pragma unroll
        for (int j = 0; j < 16; ++j) pex[0][j][ptb] = gp[j];
        #pragma unroll
        for (int j = 0; j < 16; ++j) pex[1][j][ptb] = gp[16 + j];
    }
    __syncthreads();
    if (half == 0) {
        float g[32];
        #pragma unroll
        for (int t = 0; t < 16; ++t)
            g[t] = gelu_exact(gp[t] + pex[0][t][ptb] + b_h1[t]);
        #pragma unroll
        for (int t = 0; t < 16; ++t)
            g[16+t] = gelu_exact(gp[16+t] + pex[1][t][ptb] + b_h1[16+t]);
        float r0 = b_h2[0], r1 = b_h2[1], r2 = b_h2[2];
        #pragma unroll
        for (int t = 0; t < 32; ++t) {
            float gv = g[t];
            r0 = fmaf(gv, W_h2[t*3 + 0], r0);
            r1 = fmaf(gv, W_h2[t*3 + 1], r1);
            r2 = fmaf(gv, W_h2[t*3 + 2], r2);
        }
        out[i*3 + 0] = r0;
        out[i*3 + 1] = r1;
        out[i*3 + 2] = r2;
    }
}

// ---------------------------------------------------------------------------
extern "C" void kernel_launch(void* const* d_in, const int* in_sizes, int n_in,
                              void* d_out, int out_size, void* d_ws, size_t ws_size,
                              hipStream_t stream)
{
    const float* seg    = (const float*)d_in[0];
    const float* coord  = (const float*)d_in[1];
    const int*   order  = (const int*)d_in[2];
    const int*   gc     = (const int*)d_in[4];
    const float* W_in   = (const float*)d_in[5];
    const float* b_in   = (const float*)d_in[6];
    const float* g1     = (const float*)d_in[7];
    const float* be1    = (const float*)d_in[8];
    const float* W_qkv  = (const float*)d_in[9];
    const float* b_qkv  = (const float*)d_in[10];
    const float* rpe    = (const float*)d_in[11];
    const float* W_attn = (const float*)d_in[12];
    const float* b_attn = (const float*)d_in[13];
    const float* g2     = (const float*)d_in[14];
    const float* be2    = (const float*)d_in[15];
    const float* W_f1   = (const float*)d_in[16];
    const float* b_f1   = (const float*)d_in[17];
    const float* W_f2   = (const float*)d_in[18];
    const float* b_f2   = (const float*)d_in[19];
    const float* W_h1   = (const float*)d_in[20];
    const float* b_h1   = (const float*)d_in[21];
    const float* W_h2   = (const float*)d_in[22];
    const float* b_h2   = (const float*)d_in[23];

    // workspace layout (fp32): feat[N*64] | qkv[N*192] | attn_out[N*64]
    float* feat = (float*)d_ws;
    float* qkvb = feat + (size_t)N_PTS * 64;
    float* outw = qkvb + (size_t)N_PTS * 192;

    k_in_qkv<<<N_PTS/256, 256, 0, stream>>>(seg, coord, W_in, b_in, g1, be1,
                                            W_qkv, b_qkv, feat, qkvb);
    k_attn<<<NPATCH, 256, 0, stream>>>(qkvb, order, gc, rpe, outw);
    k_ffn<<<N_PTS/128, 256, 0, stream>>>(outw, feat, W_attn, b_attn, g2, be2,
                                         W_f1, b_f1, W_f2, b_f2,
                                         W_h1, b_h1, W_h2, b_h2, (float*)d_out);
}